// Round 2
// baseline (3621.009 us; speedup 1.0000x reference)
//
#include <hip/hip_runtime.h>

typedef unsigned int u32;
typedef unsigned long long u64;

#define ROWS 65536   // B*A
#define NB 1024
#define NA 64

__device__ __forceinline__ float dot4(float4 w, float4 x){
  return w.x*x.x + w.y*x.y + w.z*x.z + w.w*x.w;
}

// ---------------- actor_1 + attention: 8 rows per block, 128 threads ----------------
__global__ __launch_bounds__(128) void k_actor1(
    const float* __restrict__ obs, const float* __restrict__ w1, const float* __restrict__ b1,
    const float* __restrict__ lng, const float* __restrict__ lnb,
    const float* __restrict__ w2, const float* __restrict__ b2,
    const float* __restrict__ aw1, const float* __restrict__ ab1,
    const float* __restrict__ aw2, const float* __restrict__ ab2,
    const float* __restrict__ aw3, const float* __restrict__ ab3,
    float* __restrict__ thoughts, int* __restrict__ isinit)
{
  const int b0 = blockIdx.x * 8;
  const int t = threadIdx.x;
  __shared__ float4 xs[8][64];     // 8 obs rows (256 f32 each)
  __shared__ float hs[8][128];     // relu(LN(h))
  __shared__ float tb[8][128];     // thoughts
  __shared__ float ab[8][64];
  __shared__ float a2b[8][64];
  __shared__ float red[8][4];

  { const float4* og = (const float4*)(obs + (size_t)b0 * 256);
    #pragma unroll
    for (int j = 0; j < 4; j++){ int p = j * 128 + t; xs[p >> 6][p & 63] = og[p]; } }
  __syncthreads();

  // h = obs @ W1^T + b1   (thread t owns output feature t, streams W1 row t)
  float acc[8];
  #pragma unroll
  for (int r = 0; r < 8; r++) acc[r] = b1[t];
  { const float4* wr = (const float4*)(w1 + (size_t)t * 256);
    for (int j = 0; j < 64; j++){
      float4 w = wr[j];
      #pragma unroll
      for (int r = 0; r < 8; r++) acc[r] += dot4(w, xs[r][j]);
    } }

  // LayerNorm over 128 features (block = 2 waves)
  #pragma unroll
  for (int r = 0; r < 8; r++){
    float s = acc[r], s2 = acc[r] * acc[r];
    #pragma unroll
    for (int off = 32; off > 0; off >>= 1){ s += __shfl_down(s, off); s2 += __shfl_down(s2, off); }
    if ((t & 63) == 0){ red[r][t >> 6] = s; red[r][2 + (t >> 6)] = s2; }
  }
  __syncthreads();
  const float g_ = lng[t], bb_ = lnb[t];
  #pragma unroll
  for (int r = 0; r < 8; r++){
    float mu  = (red[r][0] + red[r][1]) * (1.0f/128.0f);
    float var = (red[r][2] + red[r][3]) * (1.0f/128.0f) - mu * mu;
    hs[r][t] = fmaxf((acc[r] - mu) * rsqrtf(var + 1e-5f) * g_ + bb_, 0.0f);
  }
  __syncthreads();

  // thoughts = relu(h) @ W2^T + b2
  float acc2[8];
  #pragma unroll
  for (int r = 0; r < 8; r++) acc2[r] = b2[t];
  { const float4* wr = (const float4*)(w2 + (size_t)t * 128);
    for (int j = 0; j < 32; j++){
      float4 w = wr[j];
      #pragma unroll
      for (int r = 0; r < 8; r++) acc2[r] += dot4(w, ((const float4*)hs[r])[j]);
    } }
  #pragma unroll
  for (int r = 0; r < 8; r++){
    thoughts[(size_t)(b0 + r) * 128 + t] = acc2[r];
    tb[r][t] = acc2[r];
  }
  __syncthreads();

  // attention MLP
  if (t < 64){
    float a[8];
    #pragma unroll
    for (int r = 0; r < 8; r++) a[r] = ab1[t];
    const float4* wr = (const float4*)(aw1 + (size_t)t * 128);
    for (int j = 0; j < 32; j++){
      float4 w = wr[j];
      #pragma unroll
      for (int r = 0; r < 8; r++) a[r] += dot4(w, ((const float4*)tb[r])[j]);
    }
    #pragma unroll
    for (int r = 0; r < 8; r++) ab[r][t] = fmaxf(a[r], 0.0f);
  }
  __syncthreads();
  if (t < 64){
    float a[8];
    #pragma unroll
    for (int r = 0; r < 8; r++) a[r] = ab2[t];
    const float4* wr = (const float4*)(aw2 + (size_t)t * 64);
    for (int j = 0; j < 16; j++){
      float4 w = wr[j];
      #pragma unroll
      for (int r = 0; r < 8; r++) a[r] += dot4(w, ((const float4*)ab[r])[j]);
    }
    #pragma unroll
    for (int r = 0; r < 8; r++) a2b[r][t] = fmaxf(a[r], 0.0f);
  }
  __syncthreads();
  if (t < 8){
    float p = ab3[0];
    for (int j = 0; j < 64; j++) p += aw3[j] * a2b[t][j];
    isinit[b0 + t] = (p > 0.0f) ? 1 : 0;   // sigmoid(p) > 0.5  <=>  p > 0
  }
}

// ---------------- K-nearest groups: one block per batch ----------------
__global__ __launch_bounds__(256) void k_groups(
    const float* __restrict__ thoughts, int* __restrict__ idxout)
{
  const int b = blockIdx.x;
  const int tid = threadIdx.x;
  __shared__ float T[64 * 130];
  __shared__ float sq[64];
  for (int p = tid; p < 8192; p += 256){
    T[(p >> 7) * 130 + (p & 127)] = thoughts[(size_t)b * 8192 + p];
  }
  __syncthreads();
  if (tid < 64){
    const float2* tj = (const float2*)&T[tid * 130];
    float s = 0.0f;
    #pragma unroll 8
    for (int k = 0; k < 64; k++){ float2 v = tj[k]; s += v.x*v.x + v.y*v.y; }
    sq[tid] = s;
  }
  __syncthreads();
  const int lane = tid & 63;
  const int wv = tid >> 6;
  const float2* tj = (const float2*)&T[lane * 130];
  const float sqj = sq[lane];
  for (int ii = 0; ii < 16; ii++){
    const int i = wv * 16 + ii;
    const float2* ti = (const float2*)&T[i * 130];
    float dot = 0.0f;
    #pragma unroll 8
    for (int k = 0; k < 64; k++){ float2 a = ti[k]; float2 c = tj[k]; dot += a.x*c.x + a.y*c.y; }
    float d = fmaxf(sq[i] + sqj - 2.0f*dot, 0.0f);   // clamp keeps uint-compare == float-compare
    u64 key = (((u64)__float_as_uint(d)) << 32) | (u32)lane;
    u64 mask = 0;
    for (int q = 0; q < 8; q++){
      u64 m = key;
      #pragma unroll
      for (int off = 32; off > 0; off >>= 1){ u64 o = __shfl_xor(m, off); if (o < m) m = o; }
      mask |= 1ull << (u32)(m & 63u);
      if (key == m) key = ~0ull;
    }
    if (lane == 0){
      u64 mm = mask;
      int base = (b * 64 + i) * 8;
      #pragma unroll
      for (int q = 0; q < 8; q++){ int j = (int)__builtin_ctzll(mm); mm &= mm - 1; idxout[base + q] = j; }
    }
  }
}

// ---------------- sequential gather -> bi-LSTM -> scatter: one block per batch ----------------
// 512 threads: tid>>8 = direction (0 fwd, 1 bwd), tid&255 = gate row g.
// wih row (128 f32) + whh row (64 f32) in VGPRs; Wih@X hoisted out of recurrence.
__global__ __launch_bounds__(512, 2) void k_scan(
    const float* __restrict__ thoughts, const int* __restrict__ isinit, const int* __restrict__ idx,
    const float* __restrict__ wihf, const float* __restrict__ whhf,
    const float* __restrict__ bihf, const float* __restrict__ bhhf,
    const float* __restrict__ wihb, const float* __restrict__ whhb,
    const float* __restrict__ bihb, const float* __restrict__ bhhb,
    float* __restrict__ newt)
{
  const int b = blockIdx.x;
  const int tid = threadIdx.x;
  const int dir = tid >> 8;
  const int g = tid & 255;
  __shared__ float nt[64 * 128];
  __shared__ __align__(16) float4 X4s[8 * 32];
  __shared__ float zb[2][256];
  __shared__ __align__(16) float hbv[2][64];
  __shared__ int gall[512];
  __shared__ int flags[64];
  float* X = (float*)X4s;

  const float* wih = dir ? wihb : wihf;
  const float* whh = dir ? whhb : whhf;
  float4 wihr[32];
  { const float4* wp = (const float4*)(wih + (size_t)g * 128);
    #pragma unroll
    for (int j = 0; j < 32; j++) wihr[j] = wp[j]; }
  float4 whhr[16];
  { const float4* wp = (const float4*)(whh + (size_t)g * 64);
    #pragma unroll
    for (int j = 0; j < 16; j++) whhr[j] = wp[j]; }
  const float bias = dir ? (bihb[g] + bhhb[g]) : (bihf[g] + bhhf[g]);

  for (int p = tid; p < 8192; p += 512) nt[p] = thoughts[(size_t)b * 8192 + p];
  gall[tid] = idx[(size_t)b * 512 + tid];
  if (tid < 64) flags[tid] = isinit[b * 64 + tid];
  __syncthreads();

  for (int i = 0; i < 64; i++){
    if (!flags[i]) continue;            // uniform across block
    const int* gi = &gall[i * 8];
    for (int p = tid; p < 1024; p += 512) X[p] = nt[gi[p >> 7] * 128 + (p & 127)];
    __syncthreads();

    // Zx[t] = bias + Wih[g,:] . X[t,:]  for all 8 timesteps (parallel)
    float acc[8];
    #pragma unroll
    for (int t = 0; t < 8; t++) acc[t] = bias;
    #pragma unroll
    for (int j = 0; j < 32; j++){
      float4 w = wihr[j];
      #pragma unroll
      for (int t = 0; t < 8; t++) acc[t] += dot4(w, X4s[t * 32 + j]);
    }

    // recurrence: 8 steps, fwd consumes X[s], bwd consumes X[7-s]
    float c = 0.0f;
    #pragma unroll 1
    for (int s = 0; s < 8; s++){
      float z = dir ? acc[7 - s] : acc[s];
      if (s > 0){
        const float4* h4 = (const float4*)&hbv[dir][0];
        #pragma unroll
        for (int j = 0; j < 16; j++) z += dot4(whhr[j], h4[j]);
      }
      zb[dir][g] = z;
      __syncthreads();
      if (g < 64){
        const int tt = dir ? (7 - s) : s;
        float zi = zb[dir][g], zf = zb[dir][64+g], zg = zb[dir][128+g], zo = zb[dir][192+g];
        float fi = 1.0f/(1.0f + expf(-zi));
        float ff = 1.0f/(1.0f + expf(-zf));
        float fg = tanhf(zg);
        float fo = 1.0f/(1.0f + expf(-zo));
        c = ff*c + fi*fg;
        float hn = fo * tanhf(c);
        hbv[dir][g] = hn;
        nt[gi[tt] * 128 + dir * 64 + g] = hn;
      }
      __syncthreads();
    }
  }
  for (int p = tid; p < 8192; p += 512) newt[(size_t)b * 8192 + p] = nt[p];
}

// ---------------- actor_2: 8 rows per block, 128 threads ----------------
__global__ __launch_bounds__(128) void k_actor2(
    const float* __restrict__ thoughts, const float* __restrict__ newt,
    const float* __restrict__ w1, const float* __restrict__ b1, const float* __restrict__ w2,
    float* __restrict__ out)
{
  const int b0 = blockIdx.x * 8;
  const int t = threadIdx.x;
  __shared__ float xs[8][256];
  __shared__ float ybuf[8][128];
  for (int p = t; p < 2048; p += 128){
    int r = p >> 8, c = p & 255;
    float v = (c < 128) ? thoughts[(size_t)(b0 + r) * 128 + c]
                        : newt[(size_t)(b0 + r) * 128 + (c - 128)];
    xs[r][c] = fmaxf(v, 0.0f);
  }
  __syncthreads();
  float acc[8];
  #pragma unroll
  for (int r = 0; r < 8; r++) acc[r] = b1[t];
  { const float4* wr = (const float4*)(w1 + (size_t)t * 256);
    for (int j = 0; j < 64; j++){
      float4 w = wr[j];
      #pragma unroll
      for (int r = 0; r < 8; r++) acc[r] += dot4(w, ((const float4*)xs[r])[j]);
    } }
  #pragma unroll
  for (int r = 0; r < 8; r++) ybuf[r][t] = acc[r];
  __syncthreads();
  if (t < 64){
    float a[8];
    #pragma unroll
    for (int r = 0; r < 8; r++) a[r] = 0.0f;
    const float4* wr = (const float4*)(w2 + (size_t)t * 128);
    for (int j = 0; j < 32; j++){
      float4 w = wr[j];
      #pragma unroll
      for (int r = 0; r < 8; r++) a[r] += dot4(w, ((const float4*)ybuf[r])[j]);
    }
    #pragma unroll
    for (int r = 0; r < 8; r++) out[(size_t)(b0 + r) * 64 + t] = tanhf(a[r]);
  }
}

extern "C" void kernel_launch(void* const* d_in, const int* in_sizes, int n_in,
                              void* d_out, int out_size, void* d_ws, size_t ws_size,
                              hipStream_t stream)
{
  const float* obs  = (const float*)d_in[0];
  const float* w1   = (const float*)d_in[1];
  const float* b1   = (const float*)d_in[2];
  const float* lng  = (const float*)d_in[3];
  const float* lnb  = (const float*)d_in[4];
  const float* w2   = (const float*)d_in[5];
  const float* b2   = (const float*)d_in[6];
  const float* aw1  = (const float*)d_in[7];
  const float* ab1  = (const float*)d_in[8];
  const float* aw2  = (const float*)d_in[9];
  const float* ab2  = (const float*)d_in[10];
  const float* aw3  = (const float*)d_in[11];
  const float* ab3  = (const float*)d_in[12];
  const float* wihf = (const float*)d_in[13];
  const float* whhf = (const float*)d_in[14];
  const float* bihf = (const float*)d_in[15];
  const float* bhhf = (const float*)d_in[16];
  const float* wihb = (const float*)d_in[17];
  const float* whhb = (const float*)d_in[18];
  const float* bihb = (const float*)d_in[19];
  const float* bhhb = (const float*)d_in[20];
  const float* a2w1 = (const float*)d_in[21];
  const float* a2b1 = (const float*)d_in[22];
  const float* a2w2 = (const float*)d_in[23];

  float* thoughts = (float*)d_ws;                       // 33.5 MB
  float* newt     = thoughts + (size_t)ROWS * 128;      // 33.5 MB
  int*   isinit   = (int*)(newt + (size_t)ROWS * 128);  // 256 KB
  int*   idxb     = isinit + ROWS;                      // 2 MB

  hipLaunchKernelGGL(k_actor1, dim3(ROWS / 8), dim3(128), 0, stream,
                     obs, w1, b1, lng, lnb, w2, b2, aw1, ab1, aw2, ab2, aw3, ab3,
                     thoughts, isinit);
  hipLaunchKernelGGL(k_groups, dim3(NB), dim3(256), 0, stream, thoughts, idxb);
  hipLaunchKernelGGL(k_scan, dim3(NB), dim3(512), 0, stream,
                     thoughts, isinit, idxb,
                     wihf, whhf, bihf, bhhf, wihb, whhb, bihb, bhhb, newt);
  hipLaunchKernelGGL(k_actor2, dim3(ROWS / 8), dim3(128), 0, stream,
                     thoughts, newt, a2w1, a2b1, a2w2, (float*)d_out);
}